// Round 6
// baseline (767.727 us; speedup 1.0000x reference)
//
#include <hip/hip_runtime.h>
#include <hip/hip_bf16.h>

namespace {

constexpr int C = 64, H = 128, W = 128, HK = 640, WK = 640;
constexpr long long CSTR = (long long)HK * WK;   // channel stride in fkv
constexpr int PIX = 8;            // query pixels per tile
constexpr int XD = 5 * PIX;       // 40 kv columns per tile
constexpr int NT = 16;            // tiles per block (full row: 16*8 = 128 = W)
constexpr int THREADS = 256;      // 4 waves

__device__ inline unsigned int packbf2(float lo, float hi) {
    __hip_bfloat162 h2 = __float22bfloat162_rn(make_float2(lo, hi));  // v_cvt_pk_bf16_f32
    return *reinterpret_cast<unsigned int*>(&h2);
}
__device__ inline float blo(unsigned int u) { return __uint_as_float(u << 16); }
__device__ inline float bhi(unsigned int u) { return __uint_as_float(u & 0xFFFF0000u); }

// ---------------- prep: Wqk = 0.125 * Wk^T Wq  (16 KB scratch) ----------------
__global__ void prep_wqk(const float* __restrict__ Wq, const float* __restrict__ Wk,
                         float* __restrict__ Wqk) {
    int tid = blockIdx.x * 256 + threadIdx.x;    // 4096 = 64*64
    int i = tid >> 6, j = tid & 63;
    float acc = 0.f;
    #pragma unroll 8
    for (int c = 0; c < 64; ++c) acc = fmaf(Wk[c * 64 + i], Wq[c * 64 + j], acc);
    Wqk[i * 64 + j] = 0.125f * acc;
}

// kv item j for tile tt: i = t + 256*j indexes (x4:10, y:5, c4:16), 4 float4s
// at channel strides. Issue fills F*, Write packs into swizzled slab[nxt].
#define ISSUE_ITEM(Fa, Fb, Fc, Fd, j)                                          \
    if (tt < NT) { int i = t + 256 * (j);                                      \
        if (i < 800) {                                                         \
            int x4 = i % 10, y = (i / 10) % 5, c4 = i / 50;                    \
            const float* g = kvb + (size_t)(4 * c4) * CSTR                     \
                           + (size_t)(row0 + y) * WK + (XD * tt + 4 * x4);     \
            Fa = *(const float4*)(g);                                          \
            Fb = *(const float4*)(g + CSTR);                                   \
            Fc = *(const float4*)(g + 2 * CSTR);                               \
            Fd = *(const float4*)(g + 3 * CSTR); } }

#define WRITE_ITEM(Fa, Fb, Fc, Fd, j)                                          \
    if (tt < NT) { int i = t + 256 * (j);                                      \
        if (i < 800) {                                                         \
            int x4 = i % 10, y = (i / 10) % 5, c4 = i / 50;                    \
            unsigned int* sn = &slab[nxt][0];                                  \
            const float* f0 = (const float*)&Fa; const float* f1 = (const float*)&Fb; \
            const float* f2 = (const float*)&Fc; const float* f3 = (const float*)&Fd; \
            _Pragma("unroll")                                                  \
            for (int dx = 0; dx < 4; ++dx) { int x = 4 * x4 + dx;              \
                int base = (y * XD + x) * 32, sw = (((x & 7) ^ y) << 2);       \
                sn[base + ((2 * c4)     ^ sw)] = packbf2(f0[dx], f1[dx]);      \
                sn[base + ((2 * c4 + 1) ^ sw)] = packbf2(f2[dx], f3[dx]); } } }

// ---------------- fused main: persistent (b,h) row, 16-tile pipeline ----------
__global__ __launch_bounds__(THREADS, 2)
void cag_fused(const float* __restrict__ fq, const float* __restrict__ fkv,
               const float* __restrict__ Wqk, const float* __restrict__ Wv,
               float* __restrict__ out) {
    __shared__ unsigned int slab[2][5 * XD * 32];    // 2 x 25600 B, bf16 pairs
    __shared__ float fq_lds[2][PIX * 68];            // 2 x 2176 B  [p][c]
    __shared__ float qk_lds[PIX * 68];               //     2176 B  [l][ic] f32
    __shared__ float lg[PIX * 26];                   //      832 B
    __shared__ unsigned int wsum[PIX * 36];          //     1152 B  [l][slot]

    const int t = threadIdx.x;
    const int bid = blockIdx.x;
    const int h = bid & 127;
    const int b = bid >> 7;
    const int row0 = 5 * h;
    const float* kvb = fkv + (size_t)b * C * CSTR;

    // ---- prologue: stage tile 0 into buffer 0 ----
    {
        for (int i = t; i < 800; i += THREADS) {     // 10 x4 * 5 y * 16 c4
            const int x4 = i % 10, y = (i / 10) % 5, c4 = i / 50;
            const float* g = kvb + (size_t)(4 * c4) * CSTR
                           + (size_t)(row0 + y) * WK + 4 * x4;
            float4 F0 = *(const float4*)(g);
            float4 F1 = *(const float4*)(g + CSTR);
            float4 F2 = *(const float4*)(g + 2 * CSTR);
            float4 F3 = *(const float4*)(g + 3 * CSTR);
            const float* f0 = (const float*)&F0; const float* f1 = (const float*)&F1;
            const float* f2 = (const float*)&F2; const float* f3 = (const float*)&F3;
            #pragma unroll
            for (int dx = 0; dx < 4; ++dx) {
                const int x = 4 * x4 + dx;
                const int base = (y * XD + x) * 32;
                const int sw = (((x & 7) ^ y) << 2);
                slab[0][base + ((2 * c4)     ^ sw)] = packbf2(f0[dx], f1[dx]);
                slab[0][base + ((2 * c4 + 1) ^ sw)] = packbf2(f2[dx], f3[dx]);
            }
        }
        const int c = t >> 2, p2 = t & 3;            // fq tile 0: 1 float2/thread
        float2 f2v = *(const float2*)&fq[((size_t)(b * 64 + c) << 14) + h * 128 + 2 * p2];
        fq_lds[0][(2 * p2) * 68 + c]     = f2v.x;
        fq_lds[0][(2 * p2 + 1) * 68 + c] = f2v.y;
    }
    __syncthreads();

    for (int tile = 0; tile < NT; ++tile) {
        const int cur = tile & 1, nxt = cur ^ 1;
        const int tt = tile + 1;                     // tile being prefetched
        const int w0q = PIX * tile;

        float4 A0, A1, A2, A3, B0, B1, B2, B3, C0, C1, C2, C3, D0, D1, D2, D3;
        float2 fq2;

        // ======== PHASE A: issue items 0,1 + fq(t+1); compute qk ========
        ISSUE_ITEM(A0, A1, A2, A3, 0)
        ISSUE_ITEM(B0, B1, B2, B3, 1)
        if (tt < NT) {
            const int c = t >> 2, p2 = t & 3;
            fq2 = *(const float2*)&fq[((size_t)(b * 64 + c) << 14) + h * 128
                                      + PIX * tt + 2 * p2];
        }
        {   // qk[l][i] = sum_j Wqk[i][j] * fq_lds[cur][l][j]
            const int l = t & 7, i0 = t >> 3;        // i0 in 0..31
            const float4* wr0 = (const float4*)(Wqk + i0 * 64);
            const float4* wr1 = (const float4*)(Wqk + (i0 + 32) * 64);
            const float4* fv  = (const float4*)(&fq_lds[cur][l * 68]);
            float a0 = 0.f, a1 = 0.f;
            #pragma unroll
            for (int j = 0; j < 16; ++j) {
                float4 f = fv[j], w0 = wr0[j], w1 = wr1[j];
                a0 = fmaf(w0.x, f.x, a0); a0 = fmaf(w0.y, f.y, a0);
                a0 = fmaf(w0.z, f.z, a0); a0 = fmaf(w0.w, f.w, a0);
                a1 = fmaf(w1.x, f.x, a1); a1 = fmaf(w1.y, f.y, a1);
                a1 = fmaf(w1.z, f.z, a1); a1 = fmaf(w1.w, f.w, a1);
            }
            qk_lds[l * 68 + i0]      = a0;
            qk_lds[l * 68 + i0 + 32] = a1;
        }
        __syncthreads();

        // ======== PHASE B: issue item 2; logits + softmax; write item 0 ====
        ISSUE_ITEM(C0, C1, C2, C3, 2)
        {
            const int l = t >> 5;        // pixel 0..7
            const int n = t & 31;        // kv position 0..24
            float v = -1e30f;
            if (n < 25) {
                const int ky = n / 5, kx = n - 5 * (n / 5);
                const int x = 5 * l + kx;
                const int base = (ky * XD + x) * 32;
                const int sw7 = (x & 7) ^ ky;
                const float4* qv = (const float4*)(qk_lds + l * 68);
                float acc = 0.f;
                #pragma unroll
                for (int j = 0; j < 8; ++j) {
                    uint4 u = *(const uint4*)&slab[cur][base + 4 * (j ^ sw7)];
                    float4 qa = qv[2 * j], qb = qv[2 * j + 1];
                    acc = fmaf(qa.x, blo(u.x), acc); acc = fmaf(qa.y, bhi(u.x), acc);
                    acc = fmaf(qa.z, blo(u.y), acc); acc = fmaf(qa.w, bhi(u.y), acc);
                    acc = fmaf(qb.x, blo(u.z), acc); acc = fmaf(qb.y, bhi(u.z), acc);
                    acc = fmaf(qb.z, blo(u.w), acc); acc = fmaf(qb.w, bhi(u.w), acc);
                }
                v = acc;
            }
            float m = v;
            #pragma unroll
            for (int off = 16; off; off >>= 1) m = fmaxf(m, __shfl_xor(m, off, 32));
            float e = __expf(v - m);
            float s = e;
            #pragma unroll
            for (int off = 16; off; off >>= 1) s += __shfl_xor(s, off, 32);
            if (n < 25) lg[l * 26 + n] = e / s;
        }
        WRITE_ITEM(A0, A1, A2, A3, 0)
        __syncthreads();

        // ======== PHASE C: issue item 3; wsum; write item 1 ========
        ISSUE_ITEM(D0, D1, D2, D3, 3)
        {
            const int l = t >> 5, s = t & 31;
            float alo = 0.f, ahi = 0.f;
            #pragma unroll
            for (int n2 = 0; n2 < 25; ++n2) {
                const int ky = n2 / 5, kx = n2 - 5 * ky;     // compile-time
                const int x = 5 * l + kx;
                const unsigned int u =
                    slab[cur][(ky * XD + x) * 32 + (s ^ ((((x & 7) ^ ky)) << 2))];
                const float a = lg[l * 26 + n2];
                alo = fmaf(a, blo(u), alo);
                ahi = fmaf(a, bhi(u), ahi);
            }
            wsum[l * 36 + s] = packbf2(alo, ahi);
        }
        WRITE_ITEM(B0, B1, B2, B3, 1)
        __syncthreads();

        // ======== PHASE D: out + store; write items 2,3 + fq(t+1) ========
        {
            const int p = t & 7, o0 = t >> 3;        // o0 in 0..31
            const uint4* wsr = (const uint4*)(wsum + p * 36);
            float vals[64];
            #pragma unroll
            for (int g8 = 0; g8 < 8; ++g8) {
                uint4 u = wsr[g8];
                vals[8 * g8 + 0] = blo(u.x); vals[8 * g8 + 1] = bhi(u.x);
                vals[8 * g8 + 2] = blo(u.y); vals[8 * g8 + 3] = bhi(u.y);
                vals[8 * g8 + 4] = blo(u.z); vals[8 * g8 + 5] = bhi(u.z);
                vals[8 * g8 + 6] = blo(u.w); vals[8 * g8 + 7] = bhi(u.w);
            }
            const float4* wv0 = (const float4*)(Wv + o0 * 64);
            const float4* wv1 = (const float4*)(Wv + (o0 + 32) * 64);
            float a0 = fq_lds[cur][p * 68 + o0];     // residual
            float a1 = fq_lds[cur][p * 68 + o0 + 32];
            #pragma unroll
            for (int j = 0; j < 16; ++j) {
                float4 w0 = wv0[j], w1 = wv1[j];
                a0 = fmaf(w0.x, vals[4*j+0], a0); a0 = fmaf(w0.y, vals[4*j+1], a0);
                a0 = fmaf(w0.z, vals[4*j+2], a0); a0 = fmaf(w0.w, vals[4*j+3], a0);
                a1 = fmaf(w1.x, vals[4*j+0], a1); a1 = fmaf(w1.y, vals[4*j+1], a1);
                a1 = fmaf(w1.z, vals[4*j+2], a1); a1 = fmaf(w1.w, vals[4*j+3], a1);
            }
            const size_t ob = ((size_t)(b * 64 + o0) << 14) + h * 128 + w0q + p;
            out[ob] = a0;
            out[ob + ((size_t)32 << 14)] = a1;
        }
        WRITE_ITEM(C0, C1, C2, C3, 2)
        WRITE_ITEM(D0, D1, D2, D3, 3)
        if (tt < NT) {
            const int c = t >> 2, p2 = t & 3;
            fq_lds[nxt][(2 * p2) * 68 + c]     = fq2.x;
            fq_lds[nxt][(2 * p2 + 1) * 68 + c] = fq2.y;
        }
        __syncthreads();
    }
}

} // namespace

extern "C" void kernel_launch(void* const* d_in, const int* in_sizes, int n_in,
                              void* d_out, int out_size, void* d_ws, size_t ws_size,
                              hipStream_t stream) {
    (void)in_sizes; (void)n_in; (void)ws_size; (void)out_size;
    const float* fq  = (const float*)d_in[0];
    const float* fkv = (const float*)d_in[1];
    const float* Wq  = (const float*)d_in[2];
    const float* Wk  = (const float*)d_in[3];
    const float* Wv  = (const float*)d_in[4];
    float* out = (float*)d_out;
    float* Wqk = (float*)d_ws;                      // 16 KB scratch

    prep_wqk <<<dim3(16),  dim3(256),     0, stream>>>(Wq, Wk, Wqk);
    cag_fused<<<dim3(512), dim3(THREADS), 0, stream>>>(fq, fkv, Wqk, Wv, out);
}